// Round 3
// baseline (336.956 us; speedup 1.0000x reference)
//
#include <hip/hip_runtime.h>

// LRU forward, MI355X/gfx950.
// Pipeline: prep (lambda/gamma/Bcat/Ccat/bf16-inputs) -> GEMM1 (Bu) ->
// chunked scan (32 chunks of 128, carry fix-up, in-place hs) -> GEMM2 (+skip).
// R2: XCD-compact swizzle. R3: dbuf 128^2 (613TF). R4: 256^2, 8 waves, BK=32,
// 4-deep ring, counted vmcnt (692TF, Mfma 27%). R5: fine 2-phase/K-tile pacing
// (818TF, Mfma 33%). R6: overlap schedule — R5 bracketed every ds_read burst
// away from MFMA (burst alternation: LDS and MFMA pipes strictly serialized
// block-wide). Now: READ_A(4..7) issues under MFMA16(0); MFMA16(4) moves AFTER
// the certification barrier (zero-wait register MFMA) so it overlaps the next
// iter's reads from skewed waves; 2 barriers/K-tile instead of 4.
// Certs at BAR2: vmcnt(8) = tile kt+1 landed; lgkmcnt(0) = my reads drained
// (WAR-cert for next iter's global_load_lds into buf (kt+4)&3 = kt&3).

typedef __bf16 bf16x8 __attribute__((ext_vector_type(8)));
typedef float floatx4 __attribute__((ext_vector_type(4)));

__device__ __forceinline__ unsigned short f2bf(float f) {
  unsigned u = __float_as_uint(f);
  u += 0x7fffu + ((u >> 16) & 1u);   // RNE; inputs are finite
  return (unsigned short)(u >> 16);
}
__device__ __forceinline__ float bf2f(unsigned short s) {
  return __uint_as_float(((unsigned)s) << 16);
}

// ---------------- prep kernels ----------------

__global__ void prep_params(const float* __restrict__ nu_log,
                            const float* __restrict__ theta_log,
                            float* __restrict__ lam,    // [2048] re|im
                            float* __restrict__ lamL,   // [2048] lambda^128 re|im
                            float* __restrict__ gamma)  // [1024]
{
  int h = blockIdx.x * 256 + threadIdx.x;   // exactly 1024
  float nu = expf(nu_log[h]);
  float th = expf(theta_log[h]);
  float r = expf(-nu);
  lam[h]        = r * cosf(th);
  lam[1024 + h] = r * sinf(th);
  float rL = expf(-128.0f * nu);
  lamL[h]        = rL * cosf(128.0f * th);
  lamL[1024 + h] = rL * sinf(128.0f * th);
  gamma[h] = sqrtf(1.0f - expf(-2.0f * nu) + 1e-5f);
}

__global__ void prep_B(const float* __restrict__ B_re, const float* __restrict__ B_im,
                       const float* __restrict__ gamma, unsigned short* __restrict__ Bcat)
{
  int tid = blockIdx.x * 256 + threadIdx.x;  // 2048*1024
  int n = tid >> 10;
  int d = tid & 1023;
  int h = n & 1023;
  float v = (n < 1024 ? B_re[h * 1024 + d] : B_im[h * 1024 + d]) * gamma[h];
  Bcat[tid] = f2bf(v);
}

__global__ void prep_C(const float* __restrict__ C_re, const float* __restrict__ C_im,
                       unsigned short* __restrict__ Ccat)
{
  int tid = blockIdx.x * 256 + threadIdx.x;  // 1024*2048
  int d = tid >> 11;
  int k = tid & 2047;
  float v = (k < 1024) ? C_re[d * 1024 + k] : -C_im[d * 1024 + (k - 1024)];
  Ccat[tid] = f2bf(v);
}

__global__ void conv_inputs(const float* __restrict__ in, unsigned short* __restrict__ outb)
{
  int tid = blockIdx.x * 256 + threadIdx.x;  // 16.7M/4
  float4 v = ((const float4*)in)[tid];
  unsigned lo = (unsigned)f2bf(v.x) | ((unsigned)f2bf(v.y) << 16);
  unsigned hi = (unsigned)f2bf(v.z) | ((unsigned)f2bf(v.w) << 16);
  ((uint2*)outb)[tid] = make_uint2(lo, hi);
}

// ---------------- GEMM (A: [M,K] k-contig, Bt: [N,K] k-contig) ----------------
// 256x256 tile, BK=32, 8 waves (2x4), per-wave 128x64 out via 8x4 16x16x32
// fragments (32 MFMA / wave / K-tile, two 16-MFMA clusters).
// LDS: 4-deep ring of (16KB A + 16KB B) = 128 KiB, 1 block/CU, 8 waves/CU.
// Steady-state iteration kt (reads buf kt&3, stages tile kt+3 into (kt+3)&3):
//   READ_B + READ_A[0..3] (8 ds_read_b128)
//   GLDS A-pair(kt+3)
//   BAR1 (pacing)
//   READ_A[4..7] (4 reads -> drain under MFMA16(0))
//   MFMA16(0)  [setprio]
//   GLDS B-pair(kt+3)
//   vmcnt(8) + lgkmcnt(0)  -> BAR2 (cert)
//   MFMA16(4)  [register-only, zero-wait; overlaps skewed waves' next reads]
// WAR chain: next iter's GLDS hits buf (kt+4)&3 = kt&3; all reads of kt&3 are
// lgkm-drained before BAR2(kt), and every wave issues the GLDS only after
// passing BAR2(kt). vmcnt retires in issue order; at the vmcnt(8) point the
// outstanding set is tiles kt+1,kt+2,kt+3 (12 loads) -> waits tile kt+1 (4).
// Full-block barriers bound skew to one barrier interval (arrival n of every
// wave is the same syntactic barrier), so no barrier-instance aliasing.
// LDS swizzle (measured conflict-free): row r (64B) holds its four 16B
// k-chunks at position p storing logical chunk p ^ ((r>>1)&3).
// XCD-compact swizzle: xcd=id&7 owns m-tiles [xcd*8, xcd*8+8), m-fastest.

#define GLDS(gp, lp) __builtin_amdgcn_global_load_lds(                        \
      (const __attribute__((address_space(1))) void*)(gp),                    \
      (__attribute__((address_space(3))) void*)(lp), 16, 0, 0)

#define STAGE(kt, buf) do {                                                   \
    const int _ko = (kt) * 32;                                                \
    GLDS(gA0 + _ko, &As[(buf)][lofs0]);                                       \
    GLDS(gA1 + _ko, &As[(buf)][lofs1]);                                       \
    GLDS(gB0 + _ko, &Bs[(buf)][lofs0]);                                       \
    GLDS(gB1 + _ko, &Bs[(buf)][lofs1]);                                       \
  } while (0)

#define READ_B(buf) do {                                                      \
    _Pragma("unroll")                                                         \
    for (int j = 0; j < 4; ++j) {                                             \
      const int r = wn * 64 + j * 16 + lm;                                    \
      bfr[j] = *reinterpret_cast<const bf16x8*>(                              \
          &Bs[(buf)][r * 32 + (q ^ ((r >> 1) & 3)) * 8]);                     \
    }                                                                         \
  } while (0)

#define READ_A(buf, i0) do {                                                  \
    _Pragma("unroll")                                                         \
    for (int i = 0; i < 4; ++i) {                                             \
      const int r = wm * 128 + ((i0) + i) * 16 + lm;                          \
      afr[(i0) + i] = *reinterpret_cast<const bf16x8*>(                       \
          &As[(buf)][r * 32 + (q ^ ((r >> 1) & 3)) * 8]);                     \
    }                                                                         \
  } while (0)

#define MFMA16(i0) do {                                                       \
    __builtin_amdgcn_s_setprio(1);                                            \
    _Pragma("unroll")                                                         \
    for (int i = 0; i < 4; ++i)                                               \
      _Pragma("unroll")                                                       \
      for (int j = 0; j < 4; ++j)                                             \
        acc[(i0) + i][j] = __builtin_amdgcn_mfma_f32_16x16x32_bf16(           \
            afr[(i0) + i], bfr[j], acc[(i0) + i][j], 0, 0, 0);                \
    __builtin_amdgcn_s_setprio(0);                                            \
  } while (0)

#define SB0() __builtin_amdgcn_sched_barrier(0)

#define BAR_PACE() do {                                                       \
    SB0();                                                                    \
    asm volatile("" ::: "memory");                                            \
    __builtin_amdgcn_s_barrier();                                             \
    asm volatile("" ::: "memory");                                            \
    SB0();                                                                    \
  } while (0)

// Certification barrier: vmcnt(vm) -> oldest tiles retired; lgkmcnt(0) ->
// this wave's ds_reads drained (WAR cert). sched_barrier(0) right after the
// inline-asm waitcnts (rule: hipcc hoists register-only MFMA past asm waits).
#define BAR_CERT(vm) do {                                                     \
    SB0();                                                                    \
    asm volatile("s_waitcnt vmcnt(" #vm ")" ::: "memory");                    \
    asm volatile("s_waitcnt lgkmcnt(0)" ::: "memory");                        \
    SB0();                                                                    \
    __builtin_amdgcn_s_barrier();                                             \
    asm volatile("" ::: "memory");                                            \
    SB0();                                                                    \
  } while (0)

template <int EPI>
__global__ __launch_bounds__(512, 2) void gemm256_kernel(
    const unsigned short* __restrict__ A,
    const unsigned short* __restrict__ Bt,
    void* __restrict__ Cout,
    int M, int N, int K,
    const float* __restrict__ skip_in,
    const float* __restrict__ skip_w)
{
  __shared__ __align__(16) unsigned short As[4][256 * 32];
  __shared__ __align__(16) unsigned short Bs[4][256 * 32];

  const int tid  = threadIdx.x;
  const int lane = tid & 63;
  const int wave = tid >> 6;   // 0..7
  const int wm = wave >> 2;    // 0..1 (m half)
  const int wn = wave & 3;     // 0..3 (n quarter)

  // XCD-compact tile assignment (M/256 == 64 for both GEMMs: 8 XCDs x 8 m-tiles)
  const int flat    = blockIdx.x;
  const int xcd     = flat & 7;
  const int local   = flat >> 3;
  const int m_tile  = xcd * 8 + (local & 7);
  const int n_tile  = local >> 3;
  const int m0 = m_tile * 256;
  const int n0 = n_tile * 256;

  const int ldr = lane >> 2;   // 0..15: row within a 16-row staging group
  const int pos = lane & 3;    // 16B chunk position within the 64B row
  const int lm  = lane & 15;   // fragment row (A: m, B: n)
  const int q   = lane >> 4;   // fragment k-chunk (k = q*8 + j)

  // Per-thread staging geometry (two rows per thread; 8 waves x 32 rows = 256)
  const int r0 = wave * 32 + ldr;
  const int r1 = r0 + 16;
  const int ca0 = pos ^ ((r0 >> 1) & 3);
  const int ca1 = pos ^ ((r1 >> 1) & 3);

  const unsigned short* gA0 = A  + (size_t)(m0 + r0) * K + ca0 * 8;
  const unsigned short* gA1 = A  + (size_t)(m0 + r1) * K + ca1 * 8;
  const unsigned short* gB0 = Bt + (size_t)(n0 + r0) * K + ca0 * 8;
  const unsigned short* gB1 = Bt + (size_t)(n0 + r1) * K + ca1 * 8;
  const int lofs0 = r0 * 32 + pos * 8;
  const int lofs1 = r1 * 32 + pos * 8;

  floatx4 acc[8][4];
#pragma unroll
  for (int i = 0; i < 8; ++i)
#pragma unroll
    for (int j = 0; j < 4; ++j)
      acc[i][j] = (floatx4){0.f, 0.f, 0.f, 0.f};

  const int KT = K >> 5;   // 32 or 64 K-tiles; KT >= 4 assumed

  // Prologue: prefetch tiles 0..2 into ring slots 0..2 (12 loads/thread),
  // wait for tile 0 only (8 loads = tiles 1,2 stay in flight).
  STAGE(0, 0);
  STAGE(1, 1);
  STAGE(2, 2);
  asm volatile("s_waitcnt vmcnt(8)" ::: "memory");
  __builtin_amdgcn_s_barrier();
  asm volatile("" ::: "memory");

  bf16x8 afr[8], bfr[4];

  // Steady state (2 barriers / K-tile, reads overlapped under MFMA).
  for (int kt = 0; kt + 3 < KT; ++kt) {
    const int cur = kt & 3;
    const int b3  = (kt + 3) & 3;
    const int ko3 = (kt + 3) * 32;

    READ_B(cur);
    READ_A(cur, 0);
    GLDS(gA0 + ko3, &As[b3][lofs0]);
    GLDS(gA1 + ko3, &As[b3][lofs1]);
    BAR_PACE();
    READ_A(cur, 4);        // drains under MFMA16(0)
    MFMA16(0);
    GLDS(gB0 + ko3, &Bs[b3][lofs0]);
    GLDS(gB1 + ko3, &Bs[b3][lofs1]);
    BAR_CERT(8);           // tile kt+1 landed; my reads drained
    MFMA16(4);             // register-only; overlaps skewed waves' next reads
  }

  // Tail: tiles KT-3, KT-2, KT-1 (no staging left).
  {
    const int cur = (KT - 3) & 3;
    READ_B(cur);
    READ_A(cur, 0);
    BAR_PACE();
    READ_A(cur, 4);
    MFMA16(0);
    BAR_CERT(4);           // tile KT-2 landed (only KT-1's 4 loads remain)
    MFMA16(4);
  }
  {
    const int cur = (KT - 2) & 3;
    READ_B(cur);
    READ_A(cur, 0);
    BAR_PACE();
    READ_A(cur, 4);
    MFMA16(0);
    BAR_CERT(0);           // tile KT-1 landed
    MFMA16(4);
  }
  {
    const int cur = (KT - 1) & 3;
    READ_B(cur);
    READ_A(cur, 0);
    MFMA16(0);
    READ_A(cur, 4);
    MFMA16(4);             // no barriers: epilogue touches no LDS
  }

  // Epilogue. C/D layout: col = lane&15, row = (lane>>4)*4 + reg.
#pragma unroll
  for (int i = 0; i < 8; ++i) {
#pragma unroll
    for (int j = 0; j < 4; ++j) {
      const int row0 = m0 + wm * 128 + i * 16 + q * 4;
      const int col  = n0 + wn * 64 + j * 16 + lm;
#pragma unroll
      for (int r = 0; r < 4; ++r) {
        const size_t idx = (size_t)(row0 + r) * N + col;
        if (EPI == 0) {
          ((unsigned short*)Cout)[idx] = f2bf(acc[i][j][r]);
        } else {
          ((float*)Cout)[idx] = acc[i][j][r] + skip_in[idx] * skip_w[col];
        }
      }
    }
  }
}

// ---------------- chunked scan over T ----------------
// Bu layout: [(b*4096 + t) * 2048 + h] re-plane (h<1024), +1024 im-plane.
// tid = b*32768 + c*1024 + h  (B=4, C=32 chunks of L=128, H=1024)

__global__ void scan_finals(const unsigned short* __restrict__ Bu,
                            const float* __restrict__ lam,
                            float2* __restrict__ finals)
{
  int tid = blockIdx.x * 256 + threadIdx.x;
  int h = tid & 1023, c = (tid >> 10) & 31, b = tid >> 15;
  float lre = lam[h], lim = lam[1024 + h];
  const unsigned short* p = Bu + ((size_t)(b * 4096 + c * 128) * 2048) + h;
  float yre = 0.f, yim = 0.f;
#pragma unroll 4
  for (int t = 0; t < 128; ++t) {
    float ure = bf2f(p[0]);
    float uim = bf2f(p[1024]);
    float nre = fmaf(lre, yre, fmaf(-lim, yim, ure));
    float nim = fmaf(lre, yim, fmaf(lim, yre, uim));
    yre = nre; yim = nim;
    p += 2048;
  }
  finals[tid] = make_float2(yre, yim);
}

__global__ void scan_carries(const float2* __restrict__ finals,
                             const float* __restrict__ lamL,
                             float2* __restrict__ carry)
{
  int tid = blockIdx.x * 256 + threadIdx.x;  // 4096 = B*H
  int h = tid & 1023, b = tid >> 10;
  float Lre = lamL[h], Lim = lamL[1024 + h];
  float Hre = 0.f, Him = 0.f;
  for (int c = 0; c < 32; ++c) {
    size_t i = ((size_t)(b * 32 + c) << 10) + h;
    carry[i] = make_float2(Hre, Him);   // carry INTO chunk c (H_{c-1})
    float2 f = finals[i];
    float nre = fmaf(Lre, Hre, fmaf(-Lim, Him, f.x));
    float nim = fmaf(Lre, Him, fmaf(Lim, Hre, f.y));
    Hre = nre; Him = nim;
  }
}

__global__ void scan_apply(const float* __restrict__ lam,
                           const float2* __restrict__ carry,
                           unsigned short* __restrict__ Bu)  // in-place -> hs
{
  int tid = blockIdx.x * 256 + threadIdx.x;
  int h = tid & 1023, c = (tid >> 10) & 31, b = tid >> 15;
  float lre = lam[h], lim = lam[1024 + h];
  float2 cv = carry[tid];
  float yre = cv.x, yim = cv.y;
  unsigned short* p = Bu + ((size_t)(b * 4096 + c * 128) * 2048) + h;
#pragma unroll 4
  for (int t = 0; t < 128; ++t) {
    float ure = bf2f(p[0]);
    float uim = bf2f(p[1024]);
    float nre = fmaf(lre, yre, fmaf(-lim, yim, ure));
    float nim = fmaf(lre, yim, fmaf(lim, yre, uim));
    yre = nre; yim = nim;
    p[0]    = f2bf(yre);
    p[1024] = f2bf(yim);
    p += 2048;
  }
}

// ---------------- launch ----------------

extern "C" void kernel_launch(void* const* d_in, const int* in_sizes, int n_in,
                              void* d_out, int out_size, void* d_ws, size_t ws_size,
                              hipStream_t stream)
{
  const float* inputs    = (const float*)d_in[0];
  const float* nu_log    = (const float*)d_in[1];
  const float* theta_log = (const float*)d_in[2];
  const float* B_re      = (const float*)d_in[3];
  const float* B_im      = (const float*)d_in[4];
  const float* C_re      = (const float*)d_in[5];
  const float* C_im      = (const float*)d_in[6];
  const float* D_skip    = (const float*)d_in[7];
  float* out = (float*)d_out;

  char* ws = (char*)d_ws;
  float* lam   = (float*)ws;            // 2048 f32
  float* lamL  = lam + 2048;            // 2048 f32
  float* gamma = lamL + 2048;           // 1024 f32
  unsigned short* inp_bf = (unsigned short*)(ws + (1 << 16));       // 16384x1024 bf16
  unsigned short* Bcat   = inp_bf + (size_t)16384 * 1024;           // 2048x1024
  unsigned short* Ccat   = Bcat   + (size_t)2048 * 1024;            // 1024x2048
  unsigned short* Bu     = Ccat   + (size_t)1024 * 2048;            // 16384x2048 (re|im), becomes hs in place
  float2* finals = (float2*)(Bu + (size_t)16384 * 2048);            // 131072
  float2* carry  = finals + 131072;                                 // 131072
  // total ws use ~111 MB

  prep_params<<<4,    256, 0, stream>>>(nu_log, theta_log, lam, lamL, gamma);
  prep_B     <<<8192, 256, 0, stream>>>(B_re, B_im, gamma, Bcat);
  prep_C     <<<8192, 256, 0, stream>>>(C_re, C_im, Ccat);
  conv_inputs<<<16384,256, 0, stream>>>(inputs, inp_bf);

  // GEMM1: Bu[bt, n] = inputs @ Bcat^T   (M=16384, N=2048, K=1024) -> 64x8 tiles
  gemm256_kernel<0><<<512, 512, 0, stream>>>(
      inp_bf, Bcat, Bu, 16384, 2048, 1024, nullptr, nullptr);

  scan_finals <<<512, 256, 0, stream>>>(Bu, lam, finals);
  scan_carries<<<16,  256, 0, stream>>>(finals, lamL, carry);
  scan_apply  <<<512, 256, 0, stream>>>(lam, carry, Bu);   // Bu -> hs in place

  // GEMM2: out[bt, d] = hs @ Ccat^T + inputs * D_skip  (M=16384, N=1024, K=2048) -> 64x4 tiles
  gemm256_kernel<1><<<256, 512, 0, stream>>>(
      Bu, Ccat, out, 16384, 1024, 2048, inputs, D_skip);
}

// Round 6
// 327.684 us; speedup vs baseline: 1.0283x; 1.0283x over previous
//
#include <hip/hip_runtime.h>

// LRU forward, MI355X/gfx950.
// Pipeline: prep (lambda/gamma/Bcat/Ccat/bf16-inputs) -> GEMM1 (Bu) ->
// chunked scan (32 chunks of 128, carry fix-up, in-place hs) -> GEMM2 (+skip).
// R4: 256^2, 8 waves, BK=32, ring-4, counted vmcnt (692TF). R5: fine pacing,
// lgkm BEFORE barrier (818TF). R6: reads after barrier (null). R7/R8 FAILED:
// B double-bank pushed unified regs to 272 > the HARD 256 cap (8-wave block
// => 2 waves/SIMD => 256 regs/wave max, regardless of launch_bounds) ->
// scratch spills -> spill buffer ops corrupt counted vmcnt -> garbage tiles.
// LESSON: 512-thread blocks cap at 256 unified regs; counted-vmcnt schedules
// tolerate ZERO compiler-inserted VMEM (spills). R6's reg set (128 VGPR +
// 128 AGPR, exactly 256) is the proven budget — R9 keeps it identical.
// R9: m201-faithful wait placement: {ds_reads; GLDS; barrier; lgkmcnt(0);
// MFMA}. Reads drain DURING the barrier wait (overlapped with other waves'
// arrival); post-barrier lgkm(0) is then ~free. R5 drained pre-barrier
// (serial slowest-wave drain + bar + MFMA); R6 read post-barrier (exposed).
// Scan kernels reverted to R5-verified versions (single-variable round).

typedef __bf16 bf16x8 __attribute__((ext_vector_type(8)));
typedef float floatx4 __attribute__((ext_vector_type(4)));

__device__ __forceinline__ unsigned short f2bf(float f) {
  unsigned u = __float_as_uint(f);
  u += 0x7fffu + ((u >> 16) & 1u);   // RNE; inputs are finite
  return (unsigned short)(u >> 16);
}
__device__ __forceinline__ float bf2f(unsigned short s) {
  return __uint_as_float(((unsigned)s) << 16);
}

// ---------------- prep kernels ----------------

__global__ void prep_params(const float* __restrict__ nu_log,
                            const float* __restrict__ theta_log,
                            float* __restrict__ lam,    // [2048] re|im
                            float* __restrict__ lamL,   // [2048] lambda^128 re|im
                            float* __restrict__ gamma)  // [1024]
{
  int h = blockIdx.x * 256 + threadIdx.x;   // exactly 1024
  float nu = expf(nu_log[h]);
  float th = expf(theta_log[h]);
  float r = expf(-nu);
  lam[h]        = r * cosf(th);
  lam[1024 + h] = r * sinf(th);
  float rL = expf(-128.0f * nu);
  lamL[h]        = rL * cosf(128.0f * th);
  lamL[1024 + h] = rL * sinf(128.0f * th);
  gamma[h] = sqrtf(1.0f - expf(-2.0f * nu) + 1e-5f);
}

__global__ void prep_B(const float* __restrict__ B_re, const float* __restrict__ B_im,
                       const float* __restrict__ gamma, unsigned short* __restrict__ Bcat)
{
  int tid = blockIdx.x * 256 + threadIdx.x;  // 2048*1024
  int n = tid >> 10;
  int d = tid & 1023;
  int h = n & 1023;
  float v = (n < 1024 ? B_re[h * 1024 + d] : B_im[h * 1024 + d]) * gamma[h];
  Bcat[tid] = f2bf(v);
}

__global__ void prep_C(const float* __restrict__ C_re, const float* __restrict__ C_im,
                       unsigned short* __restrict__ Ccat)
{
  int tid = blockIdx.x * 256 + threadIdx.x;  // 1024*2048
  int d = tid >> 11;
  int k = tid & 2047;
  float v = (k < 1024) ? C_re[d * 1024 + k] : -C_im[d * 1024 + (k - 1024)];
  Ccat[tid] = f2bf(v);
}

__global__ void conv_inputs(const float* __restrict__ in, unsigned short* __restrict__ outb)
{
  int tid = blockIdx.x * 256 + threadIdx.x;  // 16.7M/4
  float4 v = ((const float4*)in)[tid];
  unsigned lo = (unsigned)f2bf(v.x) | ((unsigned)f2bf(v.y) << 16);
  unsigned hi = (unsigned)f2bf(v.z) | ((unsigned)f2bf(v.w) << 16);
  ((uint2*)outb)[tid] = make_uint2(lo, hi);
}

// ---------------- GEMM (A: [M,K] k-contig, Bt: [N,K] k-contig) ----------------
// 256x256 tile, BK=32, 8 waves (2x4), per-wave 128x64 via 8x4 16x16x32 frags
// (32 MFMA / wave / K-tile, two 16-MFMA phases).
// LDS ring-4 of (16KB A + 16KB B) = 128 KiB, 1 block/CU, 8 waves/CU.
// Steady K-tile kt (reads buf kt&3, stages tile kt+3 into (kt+3)&3):
//  phase A: RD_B(4) + RD_A[0..3](4) ; GLDS A(kt+3) ; bar ; lgkm(0) ;
//           setprio + MFMA16(0)
//  phase B: RD_A[4..7](4) ; GLDS B(kt+3) ; vmcnt(8) ; bar ; lgkm(0) ;
//           setprio + MFMA16(4)
// vmcnt ledger at phase-B vmcnt(8): outstanding = tiles kt+1(4), kt+2(4),
// kt+3(4) = 12 -> retires tile kt+1 before any wave reads it (next phase A,
// post-barrier). Tails: vmcnt(4) then vmcnt(0); final tile barrier-free.
// WAR on GLDS target (slot (kt+3)&3 = (kt-1)&3, holds tile kt-1): its last
// reads issued pre-barrier one full phase earlier; GLDS write data arrives
// >=400cy after issue vs ~100cy ds_read drain -> no overlap (same latency-
// gap argument the passing R4-R6 kernels relied on).
// LDS swizzle (measured conflict-free): row r (64B) holds its four 16B
// k-chunks at position p storing logical chunk p ^ ((r>>1)&3).
// XCD-compact swizzle: xcd=id&7 owns m-tiles [xcd*8, xcd*8+8), m-fastest.

#define GLDS(gp, lp) __builtin_amdgcn_global_load_lds(                        \
      (const __attribute__((address_space(1))) void*)(gp),                    \
      (__attribute__((address_space(3))) void*)(lp), 16, 0, 0)

#define STAGE(kt, buf) do {                                                   \
    const int _ko = (kt) * 32;                                                \
    GLDS(gA0 + _ko, &As[(buf)][lofs0]);                                       \
    GLDS(gA1 + _ko, &As[(buf)][lofs1]);                                       \
    GLDS(gB0 + _ko, &Bs[(buf)][lofs0]);                                       \
    GLDS(gB1 + _ko, &Bs[(buf)][lofs1]);                                       \
  } while (0)

#define GLDS_A(kt) do {                                                       \
    const int _ko = (kt) * 32;  const int _b = (kt) & 3;                      \
    GLDS(gA0 + _ko, &As[_b][lofs0]);                                          \
    GLDS(gA1 + _ko, &As[_b][lofs1]);                                          \
  } while (0)

#define GLDS_B(kt) do {                                                       \
    const int _ko = (kt) * 32;  const int _b = (kt) & 3;                      \
    GLDS(gB0 + _ko, &Bs[_b][lofs0]);                                          \
    GLDS(gB1 + _ko, &Bs[_b][lofs1]);                                          \
  } while (0)

#define RD_B(buf) do {                                                        \
    _Pragma("unroll")                                                         \
    for (int j = 0; j < 4; ++j) {                                             \
      const int r = wn * 64 + j * 16 + lm;                                    \
      bfr[j] = *reinterpret_cast<const bf16x8*>(                              \
          &Bs[(buf)][r * 32 + (q ^ ((r >> 1) & 3)) * 8]);                     \
    }                                                                         \
  } while (0)

#define RD_A(buf, i0) do {                                                    \
    _Pragma("unroll")                                                         \
    for (int i = 0; i < 4; ++i) {                                             \
      const int r = wm * 128 + ((i0) + i) * 16 + lm;                          \
      afr[(i0) + i] = *reinterpret_cast<const bf16x8*>(                       \
          &As[(buf)][r * 32 + (q ^ ((r >> 1) & 3)) * 8]);                     \
    }                                                                         \
  } while (0)

#define MFMA16(i0) do {                                                       \
    __builtin_amdgcn_s_setprio(1);                                            \
    _Pragma("unroll")                                                         \
    for (int i = 0; i < 4; ++i)                                               \
      _Pragma("unroll")                                                       \
      for (int j = 0; j < 4; ++j)                                             \
        acc[(i0) + i][j] = __builtin_amdgcn_mfma_f32_16x16x32_bf16(           \
            afr[(i0) + i], bfr[j], acc[(i0) + i][j], 0, 0, 0);                \
    __builtin_amdgcn_s_setprio(0);                                            \
  } while (0)

#define SB0() __builtin_amdgcn_sched_barrier(0)

#define VMW(n) do {                                                           \
    SB0();                                                                    \
    asm volatile("s_waitcnt vmcnt(" #n ")" ::: "memory");                     \
    SB0();                                                                    \
  } while (0)

#define BAR() do {                                                            \
    SB0();                                                                    \
    asm volatile("" ::: "memory");                                            \
    __builtin_amdgcn_s_barrier();                                             \
    asm volatile("" ::: "memory");                                            \
    SB0();                                                                    \
  } while (0)

// Post-barrier drain of this wave's ds_reads (issued pre-barrier, so they
// drained during the barrier wait). SB0 after the asm wait pins the MFMA
// (rule: hipcc hoists register-only MFMA past inline-asm waitcnts).
#define LGKM0() do {                                                          \
    asm volatile("s_waitcnt lgkmcnt(0)" ::: "memory");                        \
    SB0();                                                                    \
  } while (0)

// Steady body for K-tile kt_ (stages tile kt_+3).
#define BODY(kt_) do {                                                        \
    const int _cur = (kt_) & 3;                                               \
    /* phase A */                                                             \
    RD_B(_cur);                                                               \
    RD_A(_cur, 0);                                                            \
    GLDS_A((kt_) + 3);                                                        \
    BAR();                                                                    \
    LGKM0();                                                                  \
    MFMA16(0);                                                                \
    /* phase B */                                                             \
    RD_A(_cur, 4);                                                            \
    GLDS_B((kt_) + 3);                                                        \
    VMW(8);                                                                   \
    BAR();                                                                    \
    LGKM0();                                                                  \
    MFMA16(4);                                                                \
  } while (0)

// Tail body: no staging; vm_ = counted wait for the next tile.
#define TAIL(kt_, vm_) do {                                                   \
    const int _cur = (kt_) & 3;                                               \
    RD_B(_cur);                                                               \
    RD_A(_cur, 0);                                                            \
    BAR();                                                                    \
    LGKM0();                                                                  \
    MFMA16(0);                                                                \
    RD_A(_cur, 4);                                                            \
    VMW(vm_);                                                                 \
    BAR();                                                                    \
    LGKM0();                                                                  \
    MFMA16(4);                                                                \
  } while (0)

template <int EPI>
__global__ __launch_bounds__(512, 2) void gemm256_kernel(
    const unsigned short* __restrict__ A,
    const unsigned short* __restrict__ Bt,
    void* __restrict__ Cout,
    int M, int N, int K,
    const float* __restrict__ skip_in,
    const float* __restrict__ skip_w)
{
  __shared__ __align__(16) unsigned short As[4][256 * 32];
  __shared__ __align__(16) unsigned short Bs[4][256 * 32];

  const int tid  = threadIdx.x;
  const int lane = tid & 63;
  const int wave = tid >> 6;   // 0..7
  const int wm = wave >> 2;    // 0..1 (m half)
  const int wn = wave & 3;     // 0..3 (n quarter)

  // XCD-compact tile assignment (M/256 == 64 for both GEMMs: 8 XCDs x 8 m-tiles)
  const int flat    = blockIdx.x;
  const int xcd     = flat & 7;
  const int local   = flat >> 3;
  const int m_tile  = xcd * 8 + (local & 7);
  const int n_tile  = local >> 3;
  const int m0 = m_tile * 256;
  const int n0 = n_tile * 256;

  const int ldr = lane >> 2;   // 0..15: row within a 16-row staging group
  const int pos = lane & 3;    // 16B chunk position within the 64B row
  const int lm  = lane & 15;   // fragment row (A: m, B: n)
  const int q   = lane >> 4;   // fragment k-chunk (k = q*8 + j)

  // Per-thread staging geometry (two rows per thread; 8 waves x 32 rows = 256)
  const int r0 = wave * 32 + ldr;
  const int r1 = r0 + 16;
  const int ca0 = pos ^ ((r0 >> 1) & 3);
  const int ca1 = pos ^ ((r1 >> 1) & 3);

  const unsigned short* gA0 = A  + (size_t)(m0 + r0) * K + ca0 * 8;
  const unsigned short* gA1 = A  + (size_t)(m0 + r1) * K + ca1 * 8;
  const unsigned short* gB0 = Bt + (size_t)(n0 + r0) * K + ca0 * 8;
  const unsigned short* gB1 = Bt + (size_t)(n0 + r1) * K + ca1 * 8;
  const int lofs0 = r0 * 32 + pos * 8;
  const int lofs1 = r1 * 32 + pos * 8;

  floatx4 acc[8][4];
#pragma unroll
  for (int i = 0; i < 8; ++i)
#pragma unroll
    for (int j = 0; j < 4; ++j)
      acc[i][j] = (floatx4){0.f, 0.f, 0.f, 0.f};

  const int KT = K >> 5;   // 32 or 64 K-tiles; KT >= 4

  bf16x8 afr[8], bfr[4];

  // Prologue: prefetch tiles 0..2 into ring slots 0..2 (12 loads/thread),
  // wait for tile 0 only (8 loads = tiles 1,2 stay in flight), barrier so
  // every wave's tile-0 loads are retired before anyone reads.
  STAGE(0, 0);
  STAGE(1, 1);
  STAGE(2, 2);
  VMW(8);
  BAR();

  for (int kt = 0; kt + 3 < KT; ++kt)
    BODY(kt);

  TAIL(KT - 3, 4);   // tile KT-2 landed (KT-1's 4 loads stay in flight)
  TAIL(KT - 2, 0);   // tile KT-1 landed
  {
    const int _cur = (KT - 1) & 3;
    RD_B(_cur);
    RD_A(_cur, 0);
    LGKM0();
    MFMA16(0);
    RD_A(_cur, 4);
    LGKM0();
    MFMA16(4);       // no barriers: epilogue touches no LDS
  }

  // Epilogue. C/D layout: col = lane&15, row = (lane>>4)*4 + reg.
#pragma unroll
  for (int i = 0; i < 8; ++i) {
#pragma unroll
    for (int j = 0; j < 4; ++j) {
      const int row0 = m0 + wm * 128 + i * 16 + q * 4;
      const int col  = n0 + wn * 64 + j * 16 + lm;
#pragma unroll
      for (int r = 0; r < 4; ++r) {
        const size_t idx = (size_t)(row0 + r) * N + col;
        if (EPI == 0) {
          ((unsigned short*)Cout)[idx] = f2bf(acc[i][j][r]);
        } else {
          ((float*)Cout)[idx] = acc[i][j][r] + skip_in[idx] * skip_w[col];
        }
      }
    }
  }
}

// ---------------- chunked scan over T ----------------
// Bu layout: [(b*4096 + t) * 2048 + h] re-plane (h<1024), +1024 im-plane.
// tid = b*32768 + c*1024 + h  (B=4, C=32 chunks of L=128, H=1024)

__global__ void scan_finals(const unsigned short* __restrict__ Bu,
                            const float* __restrict__ lam,
                            float2* __restrict__ finals)
{
  int tid = blockIdx.x * 256 + threadIdx.x;
  int h = tid & 1023, c = (tid >> 10) & 31, b = tid >> 15;
  float lre = lam[h], lim = lam[1024 + h];
  const unsigned short* p = Bu + ((size_t)(b * 4096 + c * 128) * 2048) + h;
  float yre = 0.f, yim = 0.f;
#pragma unroll 4
  for (int t = 0; t < 128; ++t) {
    float ure = bf2f(p[0]);
    float uim = bf2f(p[1024]);
    float nre = fmaf(lre, yre, fmaf(-lim, yim, ure));
    float nim = fmaf(lre, yim, fmaf(lim, yre, uim));
    yre = nre; yim = nim;
    p += 2048;
  }
  finals[tid] = make_float2(yre, yim);
}

__global__ void scan_carries(const float2* __restrict__ finals,
                             const float* __restrict__ lamL,
                             float2* __restrict__ carry)
{
  int tid = blockIdx.x * 256 + threadIdx.x;  // 4096 = B*H
  int h = tid & 1023, b = tid >> 10;
  float Lre = lamL[h], Lim = lamL[1024 + h];
  float Hre = 0.f, Him = 0.f;
  for (int c = 0; c < 32; ++c) {
    size_t i = ((size_t)(b * 32 + c) << 10) + h;
    carry[i] = make_float2(Hre, Him);   // carry INTO chunk c (H_{c-1})
    float2 f = finals[i];
    float nre = fmaf(Lre, Hre, fmaf(-Lim, Him, f.x));
    float nim = fmaf(Lre, Him, fmaf(Lim, Hre, f.y));
    Hre = nre; Him = nim;
  }
}

__global__ void scan_apply(const float* __restrict__ lam,
                           const float2* __restrict__ carry,
                           unsigned short* __restrict__ Bu)  // in-place -> hs
{
  int tid = blockIdx.x * 256 + threadIdx.x;
  int h = tid & 1023, c = (tid >> 10) & 31, b = tid >> 15;
  float lre = lam[h], lim = lam[1024 + h];
  float2 cv = carry[tid];
  float yre = cv.x, yim = cv.y;
  unsigned short* p = Bu + ((size_t)(b * 4096 + c * 128) * 2048) + h;
#pragma unroll 4
  for (int t = 0; t < 128; ++t) {
    float ure = bf2f(p[0]);
    float uim = bf2f(p[1024]);
    float nre = fmaf(lre, yre, fmaf(-lim, yim, ure));
    float nim = fmaf(lre, yim, fmaf(lim, yre, uim));
    yre = nre; yim = nim;
    p[0]    = f2bf(yre);
    p[1024] = f2bf(yim);
    p += 2048;
  }
}

// ---------------- launch ----------------

extern "C" void kernel_launch(void* const* d_in, const int* in_sizes, int n_in,
                              void* d_out, int out_size, void* d_ws, size_t ws_size,
                              hipStream_t stream)
{
  const float* inputs    = (const float*)d_in[0];
  const float* nu_log    = (const float*)d_in[1];
  const float* theta_log = (const float*)d_in[2];
  const float* B_re      = (const float*)d_in[3];
  const float* B_im      = (const float*)d_in[4];
  const float* C_re      = (const float*)d_in[5];
  const float* C_im      = (const float*)d_in[6];
  const float* D_skip    = (const float*)d_in[7];
  float* out = (float*)d_out;

  char* ws = (char*)d_ws;
  float* lam   = (float*)ws;            // 2048 f32
  float* lamL  = lam + 2048;            // 2048 f32 (lambda^128)
  float* gamma = lamL + 2048;           // 1024 f32
  unsigned short* inp_bf = (unsigned short*)(ws + (1 << 16));       // 16384x1024 bf16
  unsigned short* Bcat   = inp_bf + (size_t)16384 * 1024;           // 2048x1024
  unsigned short* Ccat   = Bcat   + (size_t)2048 * 1024;            // 1024x2048
  unsigned short* Bu     = Ccat   + (size_t)1024 * 2048;            // 16384x2048 (re|im), becomes hs in place
  float2* finals = (float2*)(Bu + (size_t)16384 * 2048);            // 131072
  float2* carry  = finals + 131072;                                 // 131072
  // total ws use ~111 MB

  prep_params<<<4,    256, 0, stream>>>(nu_log, theta_log, lam, lamL, gamma);
  prep_B     <<<8192, 256, 0, stream>>>(B_re, B_im, gamma, Bcat);
  prep_C     <<<8192, 256, 0, stream>>>(C_re, C_im, Ccat);
  conv_inputs<<<16384,256, 0, stream>>>(inputs, inp_bf);

  // GEMM1: Bu[bt, n] = inputs @ Bcat^T   (M=16384, N=2048, K=1024) -> 64x8 tiles
  gemm256_kernel<0><<<512, 512, 0, stream>>>(
      inp_bf, Bcat, Bu, 16384, 2048, 1024, nullptr, nullptr);

  scan_finals <<<512, 256, 0, stream>>>(Bu, lam, finals);
  scan_carries<<<16,  256, 0, stream>>>(finals, lamL, carry);
  scan_apply  <<<512, 256, 0, stream>>>(lam, carry, Bu);   // Bu -> hs in place

  // GEMM2: out[bt, d] = hs @ Ccat^T + inputs * D_skip  (M=16384, N=1024, K=2048) -> 64x4 tiles
  gemm256_kernel<1><<<256, 512, 0, stream>>>(
      Bu, Ccat, out, 16384, 1024, 2048, inputs, D_skip);
}

// Round 7
// 319.589 us; speedup vs baseline: 1.0543x; 1.0253x over previous
//
#include <hip/hip_runtime.h>

// LRU forward, MI355X/gfx950.
// Pipeline: prep (lambda/gamma/Bcat/Ccat/bf16-inputs) -> GEMM1 (Bu) ->
// chunked scan (32 chunks of 128, carry fix-up, in-place hs) -> GEMM2 (+skip).
// History: R4 ring-4 counted vmcnt (27%); R5/R6/R9 fine pacing variants ALL
// pin at 33-34% MfmaUtil = exactly serial DS(1129cy) + MFMA(1242cy) per
// K-tile: reads fed the SAME phase's MFMA -> every wave read-blocked then
// MFMA-blocked in lockstep, zero cross-pipe overlap. R7/R8 (extra reg banks)
// spilled past the HARD 256-reg cap (8-wave block) and corrupted counted
// vmcnt. R10: HALF-PHASE LOOKAHEAD WITH ZERO NEW REGISTERS — refill the
// just-died halves of afr[8]/bfr[4]:
//   P0(kt): RD_A47(kt) + GLDS_A(kt+3); lgkmcnt(4) [prev-phase 8 reads
//           drained, the 4 new ones stay in flight]; MFMA16(0)
//   P1(kt): lgkm(0) [afr47 drained under MFMA16(0)]; MFMA16(4);
//           RD_B(kt+1)+RD_A03(kt+1) [reg-WAR orders them after the
//           consuming MFMAs]; GLDS_B(kt+3); vmcnt(4); barrier
// Reads now feed the NEXT phase -> waves' DS issue overlaps other waves'
// (and their own trailing) MFMA (m114 co-schedule). 1 barrier/K-tile.
// Cert ledger: vmcnt(4) at end of kt drains tile kt+2 (outstanding =
// {A,B}(kt+2),{A,B}(kt+3) = 8 -> 4); so tile kt+1 is certified at BAR(kt-1),
// covering P1(kt)'s tile-kt+1 reads. Prologue: stage 0..2, vmcnt(4)
// (tiles 0,1 certified), barrier, pre-read bfr(0)+afr03(0).
// Tails: vmcnt(0)/no-op; last tile barrier-free. WAR per slot: GLDS_A(kt+3)
// hits As[(kt-1)&3], whose last reads (RD_A47(kt-1)) drained at the lgkm
// before BAR(kt-1) — one barrier ahead of this GLDS. Same for B.
// Reg set byte-identical to R9 (128 VGPR + 128 AGPR = the 256 cap, 0 spill).

typedef __bf16 bf16x8 __attribute__((ext_vector_type(8)));
typedef float floatx4 __attribute__((ext_vector_type(4)));

__device__ __forceinline__ unsigned short f2bf(float f) {
  unsigned u = __float_as_uint(f);
  u += 0x7fffu + ((u >> 16) & 1u);   // RNE; inputs are finite
  return (unsigned short)(u >> 16);
}
__device__ __forceinline__ float bf2f(unsigned short s) {
  return __uint_as_float(((unsigned)s) << 16);
}

// ---------------- prep kernels ----------------

__global__ void prep_params(const float* __restrict__ nu_log,
                            const float* __restrict__ theta_log,
                            float* __restrict__ lam,    // [2048] re|im
                            float* __restrict__ lamL,   // [2048] lambda^128 re|im
                            float* __restrict__ gamma)  // [1024]
{
  int h = blockIdx.x * 256 + threadIdx.x;   // exactly 1024
  float nu = expf(nu_log[h]);
  float th = expf(theta_log[h]);
  float r = expf(-nu);
  lam[h]        = r * cosf(th);
  lam[1024 + h] = r * sinf(th);
  float rL = expf(-128.0f * nu);
  lamL[h]        = rL * cosf(128.0f * th);
  lamL[1024 + h] = rL * sinf(128.0f * th);
  gamma[h] = sqrtf(1.0f - expf(-2.0f * nu) + 1e-5f);
}

__global__ void prep_B(const float* __restrict__ B_re, const float* __restrict__ B_im,
                       const float* __restrict__ gamma, unsigned short* __restrict__ Bcat)
{
  int tid = blockIdx.x * 256 + threadIdx.x;  // 2048*1024
  int n = tid >> 10;
  int d = tid & 1023;
  int h = n & 1023;
  float v = (n < 1024 ? B_re[h * 1024 + d] : B_im[h * 1024 + d]) * gamma[h];
  Bcat[tid] = f2bf(v);
}

__global__ void prep_C(const float* __restrict__ C_re, const float* __restrict__ C_im,
                       unsigned short* __restrict__ Ccat)
{
  int tid = blockIdx.x * 256 + threadIdx.x;  // 1024*2048
  int d = tid >> 11;
  int k = tid & 2047;
  float v = (k < 1024) ? C_re[d * 1024 + k] : -C_im[d * 1024 + (k - 1024)];
  Ccat[tid] = f2bf(v);
}

__global__ void conv_inputs(const float* __restrict__ in, unsigned short* __restrict__ outb)
{
  int tid = blockIdx.x * 256 + threadIdx.x;  // 16.7M/4
  float4 v = ((const float4*)in)[tid];
  unsigned lo = (unsigned)f2bf(v.x) | ((unsigned)f2bf(v.y) << 16);
  unsigned hi = (unsigned)f2bf(v.z) | ((unsigned)f2bf(v.w) << 16);
  ((uint2*)outb)[tid] = make_uint2(lo, hi);
}

// ---------------- GEMM (A: [M,K] k-contig, Bt: [N,K] k-contig) ----------------
// 256x256 tile, BK=32, 8 waves (2x4), per-wave 128x64 via 8x4 16x16x32 frags.
// LDS ring-4 of (16KB A + 16KB B) = 128 KiB, 1 block/CU, 8 waves/CU.
// LDS swizzle (measured conflict-free): row r (64B) holds its four 16B
// k-chunks at position p storing logical chunk p ^ ((r>>1)&3).
// XCD-compact swizzle: xcd=id&7 owns m-tiles [xcd*8, xcd*8+8), m-fastest.

#define GLDS(gp, lp) __builtin_amdgcn_global_load_lds(                        \
      (const __attribute__((address_space(1))) void*)(gp),                    \
      (__attribute__((address_space(3))) void*)(lp), 16, 0, 0)

#define STAGE(kt, buf) do {                                                   \
    const int _ko = (kt) * 32;                                                \
    GLDS(gA0 + _ko, &As[(buf)][lofs0]);                                       \
    GLDS(gA1 + _ko, &As[(buf)][lofs1]);                                       \
    GLDS(gB0 + _ko, &Bs[(buf)][lofs0]);                                       \
    GLDS(gB1 + _ko, &Bs[(buf)][lofs1]);                                       \
  } while (0)

#define GLDS_A(kt) do {                                                       \
    const int _ko = (kt) * 32;  const int _b = (kt) & 3;                      \
    GLDS(gA0 + _ko, &As[_b][lofs0]);                                          \
    GLDS(gA1 + _ko, &As[_b][lofs1]);                                          \
  } while (0)

#define GLDS_B(kt) do {                                                       \
    const int _ko = (kt) * 32;  const int _b = (kt) & 3;                      \
    GLDS(gB0 + _ko, &Bs[_b][lofs0]);                                          \
    GLDS(gB1 + _ko, &Bs[_b][lofs1]);                                          \
  } while (0)

#define RD_B(buf) do {                                                        \
    _Pragma("unroll")                                                         \
    for (int j = 0; j < 4; ++j) {                                             \
      const int r = wn * 64 + j * 16 + lm;                                    \
      bfr[j] = *reinterpret_cast<const bf16x8*>(                              \
          &Bs[(buf)][r * 32 + (q ^ ((r >> 1) & 3)) * 8]);                     \
    }                                                                         \
  } while (0)

#define RD_A(buf, i0) do {                                                    \
    _Pragma("unroll")                                                         \
    for (int i = 0; i < 4; ++i) {                                             \
      const int r = wm * 128 + ((i0) + i) * 16 + lm;                          \
      afr[(i0) + i] = *reinterpret_cast<const bf16x8*>(                       \
          &As[(buf)][r * 32 + (q ^ ((r >> 1) & 3)) * 8]);                     \
    }                                                                         \
  } while (0)

#define MFMA16(i0) do {                                                       \
    __builtin_amdgcn_s_setprio(1);                                            \
    _Pragma("unroll")                                                         \
    for (int i = 0; i < 4; ++i)                                               \
      _Pragma("unroll")                                                       \
      for (int j = 0; j < 4; ++j)                                             \
        acc[(i0) + i][j] = __builtin_amdgcn_mfma_f32_16x16x32_bf16(           \
            afr[(i0) + i], bfr[j], acc[(i0) + i][j], 0, 0, 0);                \
    __builtin_amdgcn_s_setprio(0);                                            \
  } while (0)

#define SB0() __builtin_amdgcn_sched_barrier(0)

#define VMW(n) do {                                                           \
    SB0();                                                                    \
    asm volatile("s_waitcnt vmcnt(" #n ")" ::: "memory");                     \
    SB0();                                                                    \
  } while (0)

// Counted DS wait (DS ops retire in issue order). SB0 after pins the MFMA
// (hipcc hoists register-only MFMA past inline-asm waitcnts).
#define LGKMC(n) do {                                                         \
    SB0();                                                                    \
    asm volatile("s_waitcnt lgkmcnt(" #n ")" ::: "memory");                   \
    SB0();                                                                    \
  } while (0)

#define BAR() do {                                                            \
    SB0();                                                                    \
    asm volatile("" ::: "memory");                                            \
    __builtin_amdgcn_s_barrier();                                             \
    asm volatile("" ::: "memory");                                            \
    SB0();                                                                    \
  } while (0)

// Steady body (stages tile kt_+3; cert vmcnt(4) = tile kt_+2 landed).
#define BODY_FULL(kt_) do {                                                   \
    const int _cur = (kt_) & 3;                                               \
    const int _nxt = ((kt_) + 1) & 3;                                         \
    RD_A(_cur, 4);             /* 4 reads: in flight under MFMA16(0) */       \
    GLDS_A((kt_) + 3);                                                        \
    LGKMC(4);                  /* prev-phase 8 reads drained */               \
    MFMA16(0);                 /* consumes afr03(kt),bfr(kt) */               \
    LGKMC(0);                  /* afr47 drained (under MFMA16(0)) */          \
    MFMA16(4);                 /* consumes afr47(kt),bfr(kt) */               \
    RD_B(_nxt);                /* refill dead halves for kt+1 */              \
    RD_A(_nxt, 0);                                                            \
    GLDS_B((kt_) + 3);                                                        \
    VMW(4);                    /* tile kt_+2 landed */                        \
    BAR();                                                                    \
  } while (0)

// Tail body: no staging; vm_ = counted cert for remaining tiles.
#define BODY_NOSTAGE(kt_, vm_) do {                                           \
    const int _cur = (kt_) & 3;                                               \
    const int _nxt = ((kt_) + 1) & 3;                                         \
    RD_A(_cur, 4);                                                            \
    LGKMC(4);                                                                 \
    MFMA16(0);                                                                \
    LGKMC(0);                                                                 \
    MFMA16(4);                                                                \
    RD_B(_nxt);                                                               \
    RD_A(_nxt, 0);                                                            \
    VMW(vm_);                                                                 \
    BAR();                                                                    \
  } while (0)

template <int EPI>
__global__ __launch_bounds__(512, 2) void gemm256_kernel(
    const unsigned short* __restrict__ A,
    const unsigned short* __restrict__ Bt,
    void* __restrict__ Cout,
    int M, int N, int K,
    const float* __restrict__ skip_in,
    const float* __restrict__ skip_w)
{
  __shared__ __align__(16) unsigned short As[4][256 * 32];
  __shared__ __align__(16) unsigned short Bs[4][256 * 32];

  const int tid  = threadIdx.x;
  const int lane = tid & 63;
  const int wave = tid >> 6;   // 0..7
  const int wm = wave >> 2;    // 0..1 (m half)
  const int wn = wave & 3;     // 0..3 (n quarter)

  // XCD-compact tile assignment (M/256 == 64 for both GEMMs: 8 XCDs x 8 m-tiles)
  const int flat    = blockIdx.x;
  const int xcd     = flat & 7;
  const int local   = flat >> 3;
  const int m_tile  = xcd * 8 + (local & 7);
  const int n_tile  = local >> 3;
  const int m0 = m_tile * 256;
  const int n0 = n_tile * 256;

  const int ldr = lane >> 2;   // 0..15: row within a 16-row staging group
  const int pos = lane & 3;    // 16B chunk position within the 64B row
  const int lm  = lane & 15;   // fragment row (A: m, B: n)
  const int q   = lane >> 4;   // fragment k-chunk (k = q*8 + j)

  // Per-thread staging geometry (two rows per thread; 8 waves x 32 rows = 256)
  const int r0 = wave * 32 + ldr;
  const int r1 = r0 + 16;
  const int ca0 = pos ^ ((r0 >> 1) & 3);
  const int ca1 = pos ^ ((r1 >> 1) & 3);

  const unsigned short* gA0 = A  + (size_t)(m0 + r0) * K + ca0 * 8;
  const unsigned short* gA1 = A  + (size_t)(m0 + r1) * K + ca1 * 8;
  const unsigned short* gB0 = Bt + (size_t)(n0 + r0) * K + ca0 * 8;
  const unsigned short* gB1 = Bt + (size_t)(n0 + r1) * K + ca1 * 8;
  const int lofs0 = r0 * 32 + pos * 8;
  const int lofs1 = r1 * 32 + pos * 8;

  floatx4 acc[8][4];
#pragma unroll
  for (int i = 0; i < 8; ++i)
#pragma unroll
    for (int j = 0; j < 4; ++j)
      acc[i][j] = (floatx4){0.f, 0.f, 0.f, 0.f};

  const int KT = K >> 5;   // 32 or 64 K-tiles; KT >= 5

  bf16x8 afr[8], bfr[4];

  // Prologue: stage tiles 0..2 (12 loads/thread); vmcnt(4) certifies tiles
  // 0 AND 1 per-wave; barrier -> block-wide; then pre-read kt=0's first-
  // phase fragments (they drain at BODY(0)'s lgkmcnt(4)).
  STAGE(0, 0);
  STAGE(1, 1);
  STAGE(2, 2);
  VMW(4);
  BAR();
  RD_B(0);
  RD_A(0, 0);

  for (int kt = 0; kt + 3 < KT; ++kt)
    BODY_FULL(kt);

  BODY_NOSTAGE(KT - 3, 0);   // cert tile KT-1 (last 4 outstanding)
  BODY_NOSTAGE(KT - 2, 0);   // nothing outstanding; barrier still paces
  {
    const int _cur = (KT - 1) & 3;
    RD_A(_cur, 4);
    LGKMC(4);
    MFMA16(0);
    LGKMC(0);
    MFMA16(4);               // no barrier: epilogue touches no LDS
  }

  // Epilogue. C/D layout: col = lane&15, row = (lane>>4)*4 + reg.
#pragma unroll
  for (int i = 0; i < 8; ++i) {
#pragma unroll
    for (int j = 0; j < 4; ++j) {
      const int row0 = m0 + wm * 128 + i * 16 + q * 4;
      const int col  = n0 + wn * 64 + j * 16 + lm;
#pragma unroll
      for (int r = 0; r < 4; ++r) {
        const size_t idx = (size_t)(row0 + r) * N + col;
        if (EPI == 0) {
          ((unsigned short*)Cout)[idx] = f2bf(acc[i][j][r]);
        } else {
          ((float*)Cout)[idx] = acc[i][j][r] + skip_in[idx] * skip_w[col];
        }
      }
    }
  }
}

// ---------------- chunked scan over T ----------------
// Bu layout: [(b*4096 + t) * 2048 + h] re-plane (h<1024), +1024 im-plane.
// tid = b*32768 + c*1024 + h  (B=4, C=32 chunks of L=128, H=1024)

__global__ void scan_finals(const unsigned short* __restrict__ Bu,
                            const float* __restrict__ lam,
                            float2* __restrict__ finals)
{
  int tid = blockIdx.x * 256 + threadIdx.x;
  int h = tid & 1023, c = (tid >> 10) & 31, b = tid >> 15;
  float lre = lam[h], lim = lam[1024 + h];
  const unsigned short* p = Bu + ((size_t)(b * 4096 + c * 128) * 2048) + h;
  float yre = 0.f, yim = 0.f;
#pragma unroll 4
  for (int t = 0; t < 128; ++t) {
    float ure = bf2f(p[0]);
    float uim = bf2f(p[1024]);
    float nre = fmaf(lre, yre, fmaf(-lim, yim, ure));
    float nim = fmaf(lre, yim, fmaf(lim, yre, uim));
    yre = nre; yim = nim;
    p += 2048;
  }
  finals[tid] = make_float2(yre, yim);
}

__global__ void scan_carries(const float2* __restrict__ finals,
                             const float* __restrict__ lamL,
                             float2* __restrict__ carry)
{
  int tid = blockIdx.x * 256 + threadIdx.x;  // 4096 = B*H
  int h = tid & 1023, b = tid >> 10;
  float Lre = lamL[h], Lim = lamL[1024 + h];
  float Hre = 0.f, Him = 0.f;
  for (int c = 0; c < 32; ++c) {
    size_t i = ((size_t)(b * 32 + c) << 10) + h;
    carry[i] = make_float2(Hre, Him);   // carry INTO chunk c (H_{c-1})
    float2 f = finals[i];
    float nre = fmaf(Lre, Hre, fmaf(-Lim, Him, f.x));
    float nim = fmaf(Lre, Him, fmaf(Lim, Hre, f.y));
    Hre = nre; Him = nim;
  }
}

__global__ void scan_apply(const float* __restrict__ lam,
                           const float2* __restrict__ carry,
                           unsigned short* __restrict__ Bu)  // in-place -> hs
{
  int tid = blockIdx.x * 256 + threadIdx.x;
  int h = tid & 1023, c = (tid >> 10) & 31, b = tid >> 15;
  float lre = lam[h], lim = lam[1024 + h];
  float2 cv = carry[tid];
  float yre = cv.x, yim = cv.y;
  unsigned short* p = Bu + ((size_t)(b * 4096 + c * 128) * 2048) + h;
#pragma unroll 4
  for (int t = 0; t < 128; ++t) {
    float ure = bf2f(p[0]);
    float uim = bf2f(p[1024]);
    float nre = fmaf(lre, yre, fmaf(-lim, yim, ure));
    float nim = fmaf(lre, yim, fmaf(lim, yre, uim));
    yre = nre; yim = nim;
    p[0]    = f2bf(yre);
    p[1024] = f2bf(yim);
    p += 2048;
  }
}

// ---------------- launch ----------------

extern "C" void kernel_launch(void* const* d_in, const int* in_sizes, int n_in,
                              void* d_out, int out_size, void* d_ws, size_t ws_size,
                              hipStream_t stream)
{
  const float* inputs    = (const float*)d_in[0];
  const float* nu_log    = (const float*)d_in[1];
  const float* theta_log = (const float*)d_in[2];
  const float* B_re      = (const float*)d_in[3];
  const float* B_im      = (const float*)d_in[4];
  const float* C_re      = (const float*)d_in[5];
  const float* C_im      = (const float*)d_in[6];
  const float* D_skip    = (const float*)d_in[7];
  float* out = (float*)d_out;

  char* ws = (char*)d_ws;
  float* lam   = (float*)ws;            // 2048 f32
  float* lamL  = lam + 2048;            // 2048 f32 (lambda^128)
  float* gamma = lamL + 2048;           // 1024 f32
  unsigned short* inp_bf = (unsigned short*)(ws + (1 << 16));       // 16384x1024 bf16
  unsigned short* Bcat   = inp_bf + (size_t)16384 * 1024;           // 2048x1024
  unsigned short* Ccat   = Bcat   + (size_t)2048 * 1024;            // 1024x2048
  unsigned short* Bu     = Ccat   + (size_t)1024 * 2048;            // 16384x2048 (re|im), becomes hs in place
  float2* finals = (float2*)(Bu + (size_t)16384 * 2048);            // 131072
  float2* carry  = finals + 131072;                                 // 131072
  // total ws use ~111 MB

  prep_params<<<4,    256, 0, stream>>>(nu_log, theta_log, lam, lamL, gamma);
  prep_B     <<<8192, 256, 0, stream>>>(B_re, B_im, gamma, Bcat);
  prep_C     <<<8192, 256, 0, stream>>>(C_re, C_im, Ccat);
  conv_inputs<<<16384,256, 0, stream>>>(inputs, inp_bf);

  // GEMM1: Bu[bt, n] = inputs @ Bcat^T   (M=16384, N=2048, K=1024) -> 64x8 tiles
  gemm256_kernel<0><<<512, 512, 0, stream>>>(
      inp_bf, Bcat, Bu, 16384, 2048, 1024, nullptr, nullptr);

  scan_finals <<<512, 256, 0, stream>>>(Bu, lam, finals);
  scan_carries<<<16,  256, 0, stream>>>(finals, lamL, carry);
  scan_apply  <<<512, 256, 0, stream>>>(lam, carry, Bu);   // Bu -> hs in place

  // GEMM2: out[bt, d] = hs @ Ccat^T + inputs * D_skip  (M=16384, N=1024, K=2048) -> 64x4 tiles
  gemm256_kernel<1><<<256, 512, 0, stream>>>(
      Bu, Ccat, out, 16384, 1024, 2048, inputs, D_skip);
}